// Round 1
// baseline (136.232 us; speedup 1.0000x reference)
//
#include <hip/hip_runtime.h>
#include <cstdint>
#include <cstddef>

// Problem constants (fixed by setup_inputs)
#define LSEQ   2048
#define CHN    512
#define NH     8
#define HD     64          // CHN / NH
#define NTAP   33          // S = 2*16+1
#define NPOS   4096        // B * L
#define MAXREC 256.0f      // HALF_S * MAX_F

__device__ __forceinline__ float silu_f(float v) {
    return v / (1.0f + expf(-v));
}

// ---------------------------------------------------------------------------
// Kernel 1: wave matvec (16 outputs per position) -> freq/phase, pure f32.
// One wave (64 lanes) per position.
// ---------------------------------------------------------------------------
__global__ __launch_bounds__(64) void wave_freq_phase(
    const float* __restrict__ x, const float* __restrict__ ww,
    const float* __restrict__ wb, float* __restrict__ freq,
    float* __restrict__ phase)
{
    int pos  = blockIdx.x;
    int lane = threadIdx.x;
    const float* xp = x + (size_t)pos * CHN + lane * 8;
    float4 xa = *(const float4*)xp;
    float4 xb = *(const float4*)(xp + 4);
    #pragma unroll
    for (int o = 0; o < 16; ++o) {
        const float* wr = ww + o * CHN + lane * 8;
        float4 wa = *(const float4*)wr;
        float4 wv = *(const float4*)(wr + 4);
        float p = xa.x*wa.x + xa.y*wa.y + xa.z*wa.z + xa.w*wa.w
                + xb.x*wv.x + xb.y*wv.y + xb.z*wv.z + xb.w*wv.w;
        #pragma unroll
        for (int off = 32; off > 0; off >>= 1) p += __shfl_xor(p, off);
        if (lane == 0) {
            float v = p + wb[o];
            float s = silu_f(v);
            if (o < 8) freq[pos * NH + o]        = 1.0f + 15.0f / (1.0f + expf(-s));
            else       phase[pos * NH + (o - 8)] = tanhf(s) * 16.0f;
        }
    }
}

// ---------------------------------------------------------------------------
// Kernel 2: tiled f32 GEMM  C[M,N] = silu(A[M,K] @ W[N,K]^T + bias)
// 64x64 block tile, 256 threads, 4x4 per-thread micro-tile, BK=32.
// ---------------------------------------------------------------------------
#define BM 64
#define BN 64
#define BK 32

__global__ __launch_bounds__(256) void gemm_nt_silu(
    const float* __restrict__ A, const float* __restrict__ W,
    const float* __restrict__ bias, float* __restrict__ C,
    int M, int N, int K)
{
    __shared__ float As[BK][BM];   // As[k][m]
    __shared__ float Ws[BK][BN];   // Ws[k][n]

    int bm  = blockIdx.x;
    int bn  = blockIdx.y;
    int tid = threadIdx.x;
    int tm  = tid >> 4;          // 0..15
    int tn  = tid & 15;          // 0..15
    int lrow = tid >> 3;         // 0..31
    int lcol = (tid & 7) * 4;    // 0,4,...,28

    float acc[4][4] = {};

    for (int k0 = 0; k0 < K; k0 += BK) {
        #pragma unroll
        for (int r = 0; r < 2; ++r) {
            int row = lrow + r * 32;
            float4 va = *(const float4*)(A + (size_t)(bm * BM + row) * K + k0 + lcol);
            As[lcol + 0][row] = va.x;
            As[lcol + 1][row] = va.y;
            As[lcol + 2][row] = va.z;
            As[lcol + 3][row] = va.w;
            float4 vw = *(const float4*)(W + (size_t)(bn * BN + row) * K + k0 + lcol);
            Ws[lcol + 0][row] = vw.x;
            Ws[lcol + 1][row] = vw.y;
            Ws[lcol + 2][row] = vw.z;
            Ws[lcol + 3][row] = vw.w;
        }
        __syncthreads();
        #pragma unroll
        for (int k = 0; k < BK; ++k) {
            float4 a = *(const float4*)&As[k][tm * 4];
            float4 b = *(const float4*)&Ws[k][tn * 4];
            float av[4] = {a.x, a.y, a.z, a.w};
            float bv[4] = {b.x, b.y, b.z, b.w};
            #pragma unroll
            for (int i = 0; i < 4; ++i)
                #pragma unroll
                for (int j = 0; j < 4; ++j)
                    acc[i][j] += av[i] * bv[j];
        }
        __syncthreads();
    }

    int colb = bn * BN + tn * 4;
    #pragma unroll
    for (int i = 0; i < 4; ++i) {
        int row = bm * BM + tm * 4 + i;
        float4 o;
        float v0 = acc[i][0], v1 = acc[i][1], v2 = acc[i][2], v3 = acc[i][3];
        if (bias) {
            v0 += bias[colb + 0]; v1 += bias[colb + 1];
            v2 += bias[colb + 2]; v3 += bias[colb + 3];
        }
        o.x = silu_f(v0); o.y = silu_f(v1); o.z = silu_f(v2); o.w = silu_f(v3);
        *(float4*)(C + (size_t)row * N + colb) = o;
    }
}

// ---------------------------------------------------------------------------
// Kernel 3: gather conv. One wave per (pos, head); lane = dim d.
// hidden[pos, h*64+d] = sum_s kern[pos,h,s] * lerp(x[b, i0, h*64+d], x[b, i1, ...])
// ---------------------------------------------------------------------------
__global__ __launch_bounds__(256) void gather_conv(
    const float* __restrict__ x, const float* __restrict__ freq,
    const float* __restrict__ phase, const float* __restrict__ kern,
    float* __restrict__ hidden)
{
    int item = blockIdx.x * 4 + (threadIdx.x >> 6);   // pos*NH + h
    int lane = threadIdx.x & 63;
    int h    = item & (NH - 1);
    int pos  = item >> 3;
    int b    = pos >> 11;                             // L = 2048
    int t    = pos & (LSEQ - 1);

    float f  = freq[pos * NH + h];
    float ph = phase[pos * NH + h];
    const float* xb = x + ((size_t)b * LSEQ) * CHN + h * HD + lane;
    const float* kp = kern + (size_t)pos * CHN + h * HD;

    float tf  = (float)t;
    float lo  = fmaxf(tf - MAXREC, 0.0f);
    float hi  = fminf(tf + MAXREC, (float)(LSEQ - 1));
    float acc = 0.0f;
    for (int s = 0; s < NTAP; ++s) {
        float p = tf + ph + (float)(s - 16) * f;
        p = fminf(fmaxf(p, lo), hi);
        float p0 = floorf(p);
        float w  = p - p0;
        int i0 = (int)p0;
        int i1 = min(i0 + 1, LSEQ - 1);
        float g0 = xb[(size_t)i0 * CHN];
        float g1 = xb[(size_t)i1 * CHN];
        acc += kp[s] * ((1.0f - w) * g0 + w * g1);
    }
    hidden[(size_t)pos * CHN + h * HD + lane] = acc;
}

// ---------------------------------------------------------------------------
extern "C" void kernel_launch(void* const* d_in, const int* in_sizes, int n_in,
                              void* d_out, int out_size, void* d_ws, size_t ws_size,
                              hipStream_t stream)
{
    const float* x        = (const float*)d_in[0];
    const float* wave_w   = (const float*)d_in[1];
    const float* wave_b   = (const float*)d_in[2];
    const float* kernel_w = (const float*)d_in[3];
    const float* kernel_b = (const float*)d_in[4];
    const float* out_w    = (const float*)d_in[5];
    float* out = (float*)d_out;

    float* freq   = (float*)d_ws;                       // [NPOS, NH]
    float* phase  = freq + (size_t)NPOS * NH;           // [NPOS, NH]
    float* kern   = phase + (size_t)NPOS * NH;          // [NPOS, CHN]
    float* hidden = kern + (size_t)NPOS * CHN;          // [NPOS, CHN]

    wave_freq_phase<<<NPOS, 64, 0, stream>>>(x, wave_w, wave_b, freq, phase);

    dim3 gg(NPOS / BM, CHN / BN);
    gemm_nt_silu<<<gg, 256, 0, stream>>>(x, kernel_w, kernel_b, kern, NPOS, CHN, CHN);

    gather_conv<<<NPOS * NH / 4, 256, 0, stream>>>(x, freq, phase, kern, hidden);

    gemm_nt_silu<<<gg, 256, 0, stream>>>(hidden, out_w, nullptr, out, NPOS, CHN, CHN);
}

// Round 2
// 79.468 us; speedup vs baseline: 1.7143x; 1.7143x over previous
//
#include <hip/hip_runtime.h>
#include <cstdint>
#include <cstddef>

#define LSEQ   2048
#define CHN    512
#define NH     8
#define HD     64
#define NTAP   33
#define NPOS   4096
#define MAXREC 256.0f

typedef __bf16 bf16x8 __attribute__((ext_vector_type(8)));
typedef float  f32x4  __attribute__((ext_vector_type(4)));

__device__ __forceinline__ float silu_f(float v) {
    return v / (1.0f + expf(-v));
}

__device__ __forceinline__ void gload_lds16(const void* g, void* l) {
    __builtin_amdgcn_global_load_lds((const __attribute__((address_space(1))) void*)g,
                                     (__attribute__((address_space(3))) void*)l, 16, 0, 0);
}

// ---------------------------------------------------------------------------
// Tiled-bf16 layout for GEMM operands ("A-layout", rows x 512):
//   tiles of [TR rows][64 k], tile (tm,tk) contiguous at (tm*8+tk)*TR*64 elems.
//   Within tile: row-major, 64 elems (128 B) per row, with k permuted per
//   32-block:  col' = 32*(k/32) + (k%4) + 4*((k/16)&1) + 8*((k%16)/4)
//   and XOR bank swizzle on the byte address: byte ^= (row&7)<<4.
//   This makes each MFMA 16x16x32 fragment one contiguous 16B ds_read_b128.
// ---------------------------------------------------------------------------
template<int TR>
__global__ __launch_bounds__(256) void convert_tiled(
    const float* __restrict__ src, __bf16* __restrict__ dst, int nchunks)
{
    int C = blockIdx.x * 256 + threadIdx.x;
    if (C >= nchunks) return;
    int tileIdx = C / (TR * 8);
    int o    = (C % (TR * 8)) * 16;     // byte offset in tile
    int rowL = o >> 7;
    int cb   = o & 127;
    int cbu  = cb ^ ((rowL & 7) << 4);  // un-swizzled byte within row
    int block = cbu >> 6;
    int g2    = (cbu >> 4) & 3;
    int rs = (tileIdx >> 3) * TR + rowL;
    int kb = (tileIdx & 7) * 64 + block * 32 + g2 * 4;
    const float* s = src + (size_t)rs * 512 + kb;
    float4 v0 = *(const float4*)s;
    float4 v1 = *(const float4*)(s + 16);
    bf16x8 r;
    r[0] = (__bf16)v0.x; r[1] = (__bf16)v0.y; r[2] = (__bf16)v0.z; r[3] = (__bf16)v0.w;
    r[4] = (__bf16)v1.x; r[5] = (__bf16)v1.y; r[6] = (__bf16)v1.z; r[7] = (__bf16)v1.w;
    *(bf16x8*)(dst + (size_t)C * 8) = r;
}

// ---------------------------------------------------------------------------
// Kernel 1: wave matvec -> freq/phase (f32, tiny)
// ---------------------------------------------------------------------------
__global__ __launch_bounds__(64) void wave_freq_phase(
    const float* __restrict__ x, const float* __restrict__ ww,
    const float* __restrict__ wb, float* __restrict__ freq,
    float* __restrict__ phase)
{
    int pos  = blockIdx.x;
    int lane = threadIdx.x;
    const float* xp = x + (size_t)pos * CHN + lane * 8;
    float4 xa = *(const float4*)xp;
    float4 xb = *(const float4*)(xp + 4);
    #pragma unroll
    for (int o = 0; o < 16; ++o) {
        const float* wr = ww + o * CHN + lane * 8;
        float4 wa = *(const float4*)wr;
        float4 wv = *(const float4*)(wr + 4);
        float p = xa.x*wa.x + xa.y*wa.y + xa.z*wa.z + xa.w*wa.w
                + xb.x*wv.x + xb.y*wv.y + xb.z*wv.z + xb.w*wv.w;
        #pragma unroll
        for (int off = 32; off > 0; off >>= 1) p += __shfl_xor(p, off);
        if (lane == 0) {
            float v = p + wb[o];
            float s = silu_f(v);
            if (o < 8) freq[pos * NH + o]        = 1.0f + 15.0f / (1.0f + expf(-s));
            else       phase[pos * NH + (o - 8)] = tanhf(s) * 16.0f;
        }
    }
}

// ---------------------------------------------------------------------------
// Kernel 2: bf16 MFMA GEMM  C[M,512] = silu(A @ W^T + bias), f32 out.
// A in tiled layout [M/128 tiles][8 k-tiles][128*64], W tiled [8][8][64*64].
// BM=128 BN=64 BK=64; 256 thr = 4 waves (2x2); wave tile 64x32 (4x2 frags).
// Double-buffered LDS, counted vmcnt(6).
// ---------------------------------------------------------------------------
__global__ __launch_bounds__(256) void gemm_mfma(
    const __bf16* __restrict__ At, const __bf16* __restrict__ Bt,
    const float* __restrict__ bias, float* __restrict__ C)
{
    __shared__ __bf16 As[2][128 * 64];
    __shared__ __bf16 Bs[2][64 * 64];

    int bm = blockIdx.x, bn = blockIdx.y;
    int tid  = threadIdx.x;
    int lane = tid & 63;
    int wid  = tid >> 6;
    int wr = wid >> 1, wc = wid & 1;
    int lg = lane >> 4, l15 = lane & 15;

    const __bf16* Abase = At + (size_t)bm * 8 * (128 * 64);
    const __bf16* Bbase = Bt + (size_t)bn * 8 * (64 * 64);

    // fragment byte offsets (swizzled) within LDS buffers
    int offA[4][2], offB[2][2];
    #pragma unroll
    for (int mi = 0; mi < 4; ++mi) {
        int row = wr * 64 + mi * 16 + l15;
        #pragma unroll
        for (int ks = 0; ks < 2; ++ks)
            offA[mi][ks] = row * 128 + (((ks << 6) | (lg << 4)) ^ ((row & 7) << 4));
    }
    #pragma unroll
    for (int ni = 0; ni < 2; ++ni) {
        int n = wc * 32 + ni * 16 + l15;
        #pragma unroll
        for (int ks = 0; ks < 2; ++ks)
            offB[ni][ks] = n * 128 + (((ks << 6) | (lg << 4)) ^ ((n & 7) << 4));
    }

    f32x4 acc[4][2] = {};

    auto stage = [&](int b, int kt) {
        const __bf16* ga = Abase + (size_t)kt * (128 * 64) + tid * 8;
        const __bf16* gb = Bbase + (size_t)kt * (64 * 64) + tid * 8;
        __bf16* la = &As[b][tid * 8];
        __bf16* lb = &Bs[b][tid * 8];
        #pragma unroll
        for (int c = 0; c < 4; ++c) gload_lds16(ga + c * 2048, la + c * 2048);
        #pragma unroll
        for (int c = 0; c < 2; ++c) gload_lds16(gb + c * 2048, lb + c * 2048);
    };

    stage(0, 0);
    #pragma unroll
    for (int kt = 0; kt < 8; ++kt) {
        int cur = kt & 1;
        if (kt < 7) stage(cur ^ 1, kt + 1);
        __builtin_amdgcn_sched_barrier(0);
        if (kt < 7) asm volatile("s_waitcnt vmcnt(6)" ::: "memory");
        else        asm volatile("s_waitcnt vmcnt(0)" ::: "memory");
        __builtin_amdgcn_s_barrier();
        const char* ab = (const char*)&As[cur][0];
        const char* bb = (const char*)&Bs[cur][0];
        #pragma unroll
        for (int ks = 0; ks < 2; ++ks) {
            bf16x8 af[4], bfr[2];
            #pragma unroll
            for (int mi = 0; mi < 4; ++mi) af[mi]  = *(const bf16x8*)(ab + offA[mi][ks]);
            #pragma unroll
            for (int ni = 0; ni < 2; ++ni) bfr[ni] = *(const bf16x8*)(bb + offB[ni][ks]);
            #pragma unroll
            for (int mi = 0; mi < 4; ++mi)
                #pragma unroll
                for (int ni = 0; ni < 2; ++ni)
                    acc[mi][ni] = __builtin_amdgcn_mfma_f32_16x16x32_bf16(
                        af[mi], bfr[ni], acc[mi][ni], 0, 0, 0);
        }
        __builtin_amdgcn_s_barrier();
    }

    // epilogue: C/D frag: col = l&15, row = (l>>4)*4 + j   [m89-verified]
    int n0 = bn * 64 + wc * 32 + l15;
    #pragma unroll
    for (int ni = 0; ni < 2; ++ni) {
        int n = n0 + ni * 16;
        float bv = bias ? bias[n] : 0.0f;
        #pragma unroll
        for (int mi = 0; mi < 4; ++mi) {
            int m = bm * 128 + wr * 64 + mi * 16 + lg * 4;
            #pragma unroll
            for (int j = 0; j < 4; ++j) {
                float v = acc[mi][ni][j] + bv;
                C[(size_t)(m + j) * 512 + n] = silu_f(v);
            }
        }
    }
}

// ---------------------------------------------------------------------------
// Kernel 3: gather conv. One wave per (pos, head); lane = dim d.
// Writes hidden directly as bf16 in the tiled GEMM layout (TR=128).
// ---------------------------------------------------------------------------
__global__ __launch_bounds__(256) void gather_conv(
    const float* __restrict__ x, const float* __restrict__ freq,
    const float* __restrict__ phase, const float* __restrict__ kern,
    __bf16* __restrict__ hb)
{
    int item = blockIdx.x * 4 + (threadIdx.x >> 6);   // pos*NH + h
    int lane = threadIdx.x & 63;
    int h    = item & (NH - 1);
    int pos  = item >> 3;
    int b    = pos >> 11;
    int t    = pos & (LSEQ - 1);

    float f  = freq[pos * NH + h];
    float ph = phase[pos * NH + h];
    const float* xb = x + ((size_t)b * LSEQ) * CHN + h * HD + lane;
    const float* kp = kern + (size_t)pos * CHN + h * HD;

    float tf  = (float)t;
    float lo  = fmaxf(tf - MAXREC, 0.0f);
    float hi  = fminf(tf + MAXREC, (float)(LSEQ - 1));
    float acc = 0.0f;
    for (int s = 0; s < NTAP; ++s) {
        float p = tf + ph + (float)(s - 16) * f;
        p = fminf(fmaxf(p, lo), hi);
        float p0 = floorf(p);
        float w  = p - p0;
        int i0 = (int)p0;
        int i1 = min(i0 + 1, LSEQ - 1);
        float g0 = xb[(size_t)i0 * CHN];
        float g1 = xb[(size_t)i1 * CHN];
        acc += kp[s] * ((1.0f - w) * g0 + w * g1);
    }

    // write in tiled+permuted+swizzled layout: k-index = h*64 + lane
    int tm = pos >> 7, rowL = pos & 127;
    int d = lane;
    int block = d >> 5, kk = d & 31;
    int colp = block * 32 + (kk & 3) + (((kk >> 4) & 1) << 2) + (((kk & 15) >> 2) << 3);
    int byteS = (colp * 2) ^ ((rowL & 7) << 4);
    hb[(size_t)(tm * 8 + h) * 8192 + rowL * 64 + (byteS >> 1)] = (__bf16)acc;
}

// ---------------------------------------------------------------------------
extern "C" void kernel_launch(void* const* d_in, const int* in_sizes, int n_in,
                              void* d_out, int out_size, void* d_ws, size_t ws_size,
                              hipStream_t stream)
{
    const float* x        = (const float*)d_in[0];
    const float* wave_w   = (const float*)d_in[1];
    const float* wave_b   = (const float*)d_in[2];
    const float* kernel_w = (const float*)d_in[3];
    const float* kernel_b = (const float*)d_in[4];
    const float* out_w    = (const float*)d_in[5];
    float* out = (float*)d_out;

    char* ws = (char*)d_ws;
    float*  freq   = (float*)ws;                        ws += (size_t)NPOS * NH * 4;   // 128K
    float*  phase  = (float*)ws;                        ws += (size_t)NPOS * NH * 4;   // 128K
    float*  kern   = (float*)ws;                        ws += (size_t)NPOS * CHN * 4;  // 8M
    __bf16* xb     = (__bf16*)ws;                       ws += (size_t)NPOS * CHN * 2;  // 4M
    __bf16* kwb    = (__bf16*)ws;                       ws += (size_t)CHN * CHN * 2;   // 512K
    __bf16* owb    = (__bf16*)ws;                       ws += (size_t)CHN * CHN * 2;   // 512K
    __bf16* hidb   = (__bf16*)ws;                       ws += (size_t)NPOS * CHN * 2;  // 4M

    convert_tiled<128><<<NPOS * CHN / 8 / 256, 256, 0, stream>>>(x, xb, NPOS * CHN / 8);
    convert_tiled<64><<<CHN * CHN / 8 / 256, 256, 0, stream>>>(kernel_w, kwb, CHN * CHN / 8);
    convert_tiled<64><<<CHN * CHN / 8 / 256, 256, 0, stream>>>(out_w, owb, CHN * CHN / 8);

    wave_freq_phase<<<NPOS, 64, 0, stream>>>(x, wave_w, wave_b, freq, phase);

    dim3 gg(NPOS / 128, CHN / 64);
    gemm_mfma<<<gg, 256, 0, stream>>>(xb, kwb, kernel_b, kern);

    gather_conv<<<NPOS * NH / 4, 256, 0, stream>>>(x, freq, phase, kern, hidb);

    gemm_mfma<<<gg, 256, 0, stream>>>(hidb, owb, nullptr, out);
}

// Round 3
// 75.428 us; speedup vs baseline: 1.8061x; 1.0536x over previous
//
#include <hip/hip_runtime.h>
#include <cstdint>
#include <cstddef>

#define LSEQ   2048
#define CHN    512
#define NH     8
#define HD     64
#define NTAP   33
#define NPOS   4096
#define MAXREC 256.0f
#define CAPOFF (2047 * 2048)

typedef __bf16 bf16x8 __attribute__((ext_vector_type(8)));
typedef float  f32x4  __attribute__((ext_vector_type(4)));

__device__ __forceinline__ float silu_f(float v) {
    return v / (1.0f + expf(-v));
}

__device__ __forceinline__ void gload_lds16(const void* g, void* l) {
    __builtin_amdgcn_global_load_lds((const __attribute__((address_space(1))) void*)g,
                                     (__attribute__((address_space(3))) void*)l, 16, 0, 0);
}

// ---------------------------------------------------------------------------
// Tiled-bf16 layout (TR=64 rows x 64 k per tile), k permuted per 32-block:
//   col' = 32*(k/32) + (k%4) + 4*((k/16)&1) + 8*((k%16)/4)
// and XOR bank swizzle on byte addr: byte ^= (row&7)<<4.
// One MFMA 16x16x32 fragment == one contiguous 16B ds_read_b128.
// ---------------------------------------------------------------------------
__global__ __launch_bounds__(256) void convert_tiled64(
    const float* __restrict__ src, __bf16* __restrict__ dst, int nchunks)
{
    int C = blockIdx.x * 256 + threadIdx.x;
    if (C >= nchunks) return;
    int tileIdx = C / (64 * 8);
    int o    = (C % (64 * 8)) * 16;     // byte offset in tile
    int rowL = o >> 7;
    int cb   = o & 127;
    int cbu  = cb ^ ((rowL & 7) << 4);
    int block = cbu >> 6;
    int g2    = (cbu >> 4) & 3;
    int rs = (tileIdx >> 3) * 64 + rowL;
    int kb = (tileIdx & 7) * 64 + block * 32 + g2 * 4;
    const float* s = src + (size_t)rs * 512 + kb;
    float4 v0 = *(const float4*)s;
    float4 v1 = *(const float4*)(s + 16);
    bf16x8 r;
    r[0] = (__bf16)v0.x; r[1] = (__bf16)v0.y; r[2] = (__bf16)v0.z; r[3] = (__bf16)v0.w;
    r[4] = (__bf16)v1.x; r[5] = (__bf16)v1.y; r[6] = (__bf16)v1.z; r[7] = (__bf16)v1.w;
    *(bf16x8*)(dst + (size_t)C * 8) = r;
}

// ---------------------------------------------------------------------------
// Kernel 1: wave matvec -> freq/phase -> packed tap table.
// tab[pos*264 + s*8 + h] = (i0 << 16) | f16bits(w)
// ---------------------------------------------------------------------------
__global__ __launch_bounds__(64) void wave_taps(
    const float* __restrict__ x, const float* __restrict__ ww,
    const float* __restrict__ wb, unsigned* __restrict__ tab)
{
    __shared__ float fph[16];   // [0..7]=freq, [8..15]=phase
    int pos  = blockIdx.x;
    int lane = threadIdx.x;
    const float* xp = x + (size_t)pos * CHN + lane * 8;
    float4 xa = *(const float4*)xp;
    float4 xv = *(const float4*)(xp + 4);
    #pragma unroll
    for (int o = 0; o < 16; ++o) {
        const float* wr = ww + o * CHN + lane * 8;
        float4 wa = *(const float4*)wr;
        float4 wv = *(const float4*)(wr + 4);
        float p = xa.x*wa.x + xa.y*wa.y + xa.z*wa.z + xa.w*wa.w
                + xv.x*wv.x + xv.y*wv.y + xv.z*wv.z + xv.w*wv.w;
        #pragma unroll
        for (int off = 32; off > 0; off >>= 1) p += __shfl_xor(p, off);
        if (lane == 0) {
            float v = p + wb[o];
            float s = silu_f(v);
            fph[o] = (o < 8) ? (1.0f + 15.0f / (1.0f + expf(-s)))
                             : (tanhf(s) * 16.0f);
        }
    }
    __syncthreads();

    int t = pos & (LSEQ - 1);
    float tf = (float)t;
    float lo = fmaxf(tf - MAXREC, 0.0f);
    float hi = fminf(tf + MAXREC, (float)(LSEQ - 1));
    for (int it = lane; it < NH * NTAP; it += 64) {
        int h = it & 7, s = it >> 3;
        float f  = fph[h];
        float ph = fph[8 + h];
        float p = (tf + ph) + (float)(s - 16) * f;
        p = fminf(fmaxf(p, lo), hi);
        float p0 = floorf(p);
        float w  = p - p0;
        int i0 = (int)p0;
        _Float16 hw = (_Float16)w;
        unsigned u = ((unsigned)i0 << 16) |
                     (unsigned)__builtin_bit_cast(unsigned short, hw);
        tab[(size_t)pos * (NH * NTAP) + it] = u;
    }
}

// ---------------------------------------------------------------------------
// Kernel 2: bf16 MFMA GEMM, BM=BN=64, BK=64, 4 waves (2x2), double-buffered.
// COMPACT: write silu'd result only for taps (n&63)<33 into kern33[pos][h][33].
// else:    write full f32 silu'd [M,512].
// ---------------------------------------------------------------------------
template<bool COMPACT>
__global__ __launch_bounds__(256) void gemm_mfma64(
    const __bf16* __restrict__ At, const __bf16* __restrict__ Bt,
    const float* __restrict__ bias, float* __restrict__ C)
{
    __shared__ __bf16 As[2][64 * 64];
    __shared__ __bf16 Bs[2][64 * 64];

    int bm = blockIdx.x, bn = blockIdx.y;
    int tid  = threadIdx.x;
    int lane = tid & 63;
    int wid  = tid >> 6;
    int wr = wid >> 1, wc = wid & 1;
    int lg = lane >> 4, l15 = lane & 15;

    const __bf16* Abase = At + (size_t)bm * 8 * 4096;
    const __bf16* Bbase = Bt + (size_t)bn * 8 * 4096;

    int offA[2][2], offB[2][2];
    #pragma unroll
    for (int mi = 0; mi < 2; ++mi) {
        int row = wr * 32 + mi * 16 + l15;
        #pragma unroll
        for (int ks = 0; ks < 2; ++ks)
            offA[mi][ks] = row * 128 + (((ks << 6) | (lg << 4)) ^ ((row & 7) << 4));
    }
    #pragma unroll
    for (int ni = 0; ni < 2; ++ni) {
        int n = wc * 32 + ni * 16 + l15;
        #pragma unroll
        for (int ks = 0; ks < 2; ++ks)
            offB[ni][ks] = n * 128 + (((ks << 6) | (lg << 4)) ^ ((n & 7) << 4));
    }

    f32x4 acc[2][2] = {};

    auto stage = [&](int b, int kt) {
        const __bf16* ga = Abase + (size_t)kt * 4096 + tid * 8;
        const __bf16* gb = Bbase + (size_t)kt * 4096 + tid * 8;
        __bf16* la = &As[b][tid * 8];
        __bf16* lb = &Bs[b][tid * 8];
        #pragma unroll
        for (int c = 0; c < 2; ++c) gload_lds16(ga + c * 2048, la + c * 2048);
        #pragma unroll
        for (int c = 0; c < 2; ++c) gload_lds16(gb + c * 2048, lb + c * 2048);
    };

    stage(0, 0);
    #pragma unroll
    for (int kt = 0; kt < 8; ++kt) {
        int cur = kt & 1;
        if (kt < 7) stage(cur ^ 1, kt + 1);
        __builtin_amdgcn_sched_barrier(0);
        if (kt < 7) asm volatile("s_waitcnt vmcnt(4)" ::: "memory");
        else        asm volatile("s_waitcnt vmcnt(0)" ::: "memory");
        __builtin_amdgcn_s_barrier();
        const char* ab = (const char*)&As[cur][0];
        const char* bb = (const char*)&Bs[cur][0];
        #pragma unroll
        for (int ks = 0; ks < 2; ++ks) {
            bf16x8 af[2], bfr[2];
            #pragma unroll
            for (int mi = 0; mi < 2; ++mi) af[mi]  = *(const bf16x8*)(ab + offA[mi][ks]);
            #pragma unroll
            for (int ni = 0; ni < 2; ++ni) bfr[ni] = *(const bf16x8*)(bb + offB[ni][ks]);
            #pragma unroll
            for (int mi = 0; mi < 2; ++mi)
                #pragma unroll
                for (int ni = 0; ni < 2; ++ni)
                    acc[mi][ni] = __builtin_amdgcn_mfma_f32_16x16x32_bf16(
                        af[mi], bfr[ni], acc[mi][ni], 0, 0, 0);
        }
        __builtin_amdgcn_s_barrier();
    }

    // C/D frag: col = l&15, row = (l>>4)*4 + j
    int n0 = bn * 64 + wc * 32 + l15;
    #pragma unroll
    for (int ni = 0; ni < 2; ++ni) {
        int n = n0 + ni * 16;
        float bv = bias ? bias[n] : 0.0f;
        #pragma unroll
        for (int mi = 0; mi < 2; ++mi) {
            int m = bm * 64 + wr * 32 + mi * 16 + lg * 4;
            #pragma unroll
            for (int j = 0; j < 4; ++j) {
                float v = silu_f(acc[mi][ni][j] + bv);
                if (COMPACT) {
                    int h = n >> 6, sc = n & 63;
                    if (sc < NTAP)
                        C[((size_t)(m + j) * NH + h) * NTAP + sc] = v;
                } else {
                    C[(size_t)(m + j) * 512 + n] = v;
                }
            }
        }
    }
}

// ---------------------------------------------------------------------------
// Kernel 3: gather conv. One wave per (t,h); lane = dim d; batch = blockIdx.y
// so the x base is wave-uniform (saddr + 32-bit voffset addressing).
// Writes hidden as bf16 in the tiled GEMM layout (TR=64).
// ---------------------------------------------------------------------------
__global__ __launch_bounds__(256, 4) void gather_conv(
    const float* __restrict__ x, const unsigned* __restrict__ tab,
    const float* __restrict__ kern33, __bf16* __restrict__ hb)
{
    int wid  = threadIdx.x >> 6;
    int lane = threadIdx.x & 63;
    int wix  = blockIdx.x * 4 + wid;     // t*8 + h
    int h = wix & 7, t = wix >> 3;
    int b = blockIdx.y;

    const char* xbase = (const char*)x + (size_t)b * (LSEQ * CHN * 4);
    int dlane = (h * HD + lane) * 4;
    int pos = b * LSEQ + t;
    const unsigned* tp = tab + (size_t)pos * (NH * NTAP) + h;
    const float*    kp = kern33 + ((size_t)pos * NH + h) * NTAP;

    float acc0 = 0.0f, acc1 = 0.0f;
    #pragma unroll
    for (int s = 0; s < NTAP; ++s) {
        unsigned u = tp[s * 8];
        float k = kp[s];
        float w = (float)__builtin_bit_cast(_Float16, (unsigned short)(u & 0xFFFFu));
        int off0 = (int)(u >> 16) << 11;
        int off1 = min(off0 + 2048, CAPOFF);
        float g0 = *(const float*)(xbase + (off0 + dlane));
        float g1 = *(const float*)(xbase + (off1 + dlane));
        float t1 = k * w;
        acc0 = fmaf(k - t1, g0, acc0);
        acc1 = fmaf(t1, g1, acc1);
    }
    float acc = acc0 + acc1;

    // tiled+permuted+swizzled bf16 write; k-index = h*64 + lane, kt = h
    int tile = (pos >> 6) * 8 + h;
    int rowL = pos & 63;
    int d = lane, blk = d >> 5, kk = d & 31;
    int colp = blk * 32 + (kk & 3) + (((kk >> 4) & 1) << 2) + (((kk & 15) >> 2) << 3);
    int byteS = (colp * 2) ^ ((rowL & 7) << 4);
    hb[(size_t)tile * 4096 + rowL * 64 + (byteS >> 1)] = (__bf16)acc;
}

// ---------------------------------------------------------------------------
extern "C" void kernel_launch(void* const* d_in, const int* in_sizes, int n_in,
                              void* d_out, int out_size, void* d_ws, size_t ws_size,
                              hipStream_t stream)
{
    const float* x        = (const float*)d_in[0];
    const float* wave_w   = (const float*)d_in[1];
    const float* wave_b   = (const float*)d_in[2];
    const float* kernel_w = (const float*)d_in[3];
    const float* kernel_b = (const float*)d_in[4];
    const float* out_w    = (const float*)d_in[5];
    float* out = (float*)d_out;

    char* ws = (char*)d_ws;
    unsigned* tab    = (unsigned*)ws;  ws += (size_t)NPOS * NH * NTAP * 4;  // 4.33 MB
    float*    kern33 = (float*)ws;     ws += (size_t)NPOS * NH * NTAP * 4;  // 4.33 MB
    __bf16*   xb     = (__bf16*)ws;    ws += (size_t)NPOS * CHN * 2;        // 4 MB
    __bf16*   kwb    = (__bf16*)ws;    ws += (size_t)CHN * CHN * 2;         // 0.5 MB
    __bf16*   owb    = (__bf16*)ws;    ws += (size_t)CHN * CHN * 2;         // 0.5 MB
    __bf16*   hidb   = xb;  // xb dead after GEMM1; gather runs after GEMM1

    convert_tiled64<<<NPOS * CHN / 8 / 256, 256, 0, stream>>>(x, xb, NPOS * CHN / 8);
    convert_tiled64<<<CHN * CHN / 8 / 256, 256, 0, stream>>>(kernel_w, kwb, CHN * CHN / 8);
    convert_tiled64<<<CHN * CHN / 8 / 256, 256, 0, stream>>>(out_w, owb, CHN * CHN / 8);

    wave_taps<<<NPOS, 64, 0, stream>>>(x, wave_w, wave_b, tab);

    dim3 gg(NPOS / 64, CHN / 64);
    gemm_mfma64<true><<<gg, 256, 0, stream>>>(xb, kwb, kernel_b, kern33);

    gather_conv<<<dim3(LSEQ * NH / 4, 2), 256, 0, stream>>>(x, tab, kern33, hidb);

    gemm_mfma64<false><<<gg, 256, 0, stream>>>(hidb, owb, nullptr, out);
}

// Round 4
// 72.592 us; speedup vs baseline: 1.8767x; 1.0391x over previous
//
#include <hip/hip_runtime.h>
#include <cstdint>
#include <cstddef>

#define LSEQ   2048
#define CHN    512
#define NH     8
#define HD     64
#define NTAP   33
#define NPOS   4096
#define MAXREC 256.0f

typedef __bf16 bf16x8 __attribute__((ext_vector_type(8)));
typedef __bf16 bf16x4 __attribute__((ext_vector_type(4)));
typedef float  f32x4  __attribute__((ext_vector_type(4)));

__device__ __forceinline__ float silu_f(float v) {
    return v / (1.0f + expf(-v));
}

__device__ __forceinline__ void gload_lds16(const void* g, void* l) {
    __builtin_amdgcn_global_load_lds((const __attribute__((address_space(1))) void*)g,
                                     (__attribute__((address_space(3))) void*)l, 16, 0, 0);
}

// ---------------------------------------------------------------------------
// Tiled-bf16 layout (64 rows x 64 k per tile), k permuted per 32-block:
//   col' = 32*(k/32) + (k%4) + 4*((k/16)&1) + 8*((k%16)/4)
// XOR bank swizzle on byte addr within row: byte ^= (row&7)<<4.
// One MFMA 16x16x32 fragment == one contiguous 16B ds_read_b128.
// ---------------------------------------------------------------------------

// Convert BOTH weight matrices in one dispatch (blockIdx.y selects).
__global__ __launch_bounds__(256) void convert_w(
    const float* __restrict__ w0, __bf16* __restrict__ d0,
    const float* __restrict__ w1, __bf16* __restrict__ d1)
{
    const float* src = blockIdx.y ? w1 : w0;
    __bf16*      dst = blockIdx.y ? d1 : d0;
    int C = blockIdx.x * 256 + threadIdx.x;          // 128 blocks: 512*512/8/256
    int tileIdx = C / (64 * 8);
    int o    = (C % (64 * 8)) * 16;
    int rowL = o >> 7;
    int cb   = o & 127;
    int cbu  = cb ^ ((rowL & 7) << 4);
    int block = cbu >> 6;
    int g2    = (cbu >> 4) & 3;
    int rs = (tileIdx >> 3) * 64 + rowL;
    int kb = (tileIdx & 7) * 64 + block * 32 + g2 * 4;
    const float* s = src + (size_t)rs * 512 + kb;
    float4 v0 = *(const float4*)s;
    float4 v1 = *(const float4*)(s + 16);
    bf16x8 r;
    r[0] = (__bf16)v0.x; r[1] = (__bf16)v0.y; r[2] = (__bf16)v0.z; r[3] = (__bf16)v0.w;
    r[4] = (__bf16)v1.x; r[5] = (__bf16)v1.y; r[6] = (__bf16)v1.z; r[7] = (__bf16)v1.w;
    *(bf16x8*)(dst + (size_t)C * 8) = r;
}

// ---------------------------------------------------------------------------
// Kernel 1: wave matvec -> freq/phase -> packed tap table
//           + FUSED x -> tiled bf16 conversion (row is already loaded).
// tab[pos*264 + s*8 + h] = (i0 << 16) | f16bits(w), i0 clamped to <= 2046.
// ---------------------------------------------------------------------------
__global__ __launch_bounds__(64) void wave_taps(
    const float* __restrict__ x, const float* __restrict__ ww,
    const float* __restrict__ wb, unsigned* __restrict__ tab,
    __bf16* __restrict__ xb)
{
    __shared__ float fph[16];   // [0..7]=freq, [8..15]=phase
    int pos  = blockIdx.x;
    int lane = threadIdx.x;
    const float* xp = x + (size_t)pos * CHN + lane * 8;
    float4 xa = *(const float4*)xp;
    float4 xv = *(const float4*)(xp + 4);

    // ---- fused tiled-bf16 store of this x row ----
    {
        int kloc = (lane * 8) & 63;          // k within tile, %8 == 0
        int kt   = lane >> 3;
        int rowL = pos & 63;
        int blk  = kloc >> 5;
        int kkA  = kloc & 31;
        int kkV  = kkA + 4;
        int colA = blk * 32 + 8 * ((kkA & 15) >> 2) + 4 * ((kkA >> 4) & 1);
        int colV = blk * 32 + 8 * ((kkV & 15) >> 2) + 4 * ((kkV >> 4) & 1);
        int sw   = (rowL & 7) << 4;
        char* base = (char*)xb + (((size_t)(pos >> 6) * 8 + kt) * 8192) + rowL * 128;
        bf16x4 va = { (__bf16)xa.x, (__bf16)xa.y, (__bf16)xa.z, (__bf16)xa.w };
        bf16x4 vv = { (__bf16)xv.x, (__bf16)xv.y, (__bf16)xv.z, (__bf16)xv.w };
        *(bf16x4*)(base + ((colA * 2) ^ sw)) = va;
        *(bf16x4*)(base + ((colV * 2) ^ sw)) = vv;
    }

    // ---- wave matvec -> freq/phase ----
    #pragma unroll
    for (int o = 0; o < 16; ++o) {
        const float* wr = ww + o * CHN + lane * 8;
        float4 wa = *(const float4*)wr;
        float4 wv = *(const float4*)(wr + 4);
        float p = xa.x*wa.x + xa.y*wa.y + xa.z*wa.z + xa.w*wa.w
                + xv.x*wv.x + xv.y*wv.y + xv.z*wv.z + xv.w*wv.w;
        #pragma unroll
        for (int off = 32; off > 0; off >>= 1) p += __shfl_xor(p, off);
        if (lane == 0) {
            float v = p + wb[o];
            float s = silu_f(v);
            fph[o] = (o < 8) ? (1.0f + 15.0f / (1.0f + expf(-s)))
                             : (tanhf(s) * 16.0f);
        }
    }
    __syncthreads();

    // ---- tap table ----
    int t = pos & (LSEQ - 1);
    float tf = (float)t;
    float lo = fmaxf(tf - MAXREC, 0.0f);
    float hi = fminf(tf + MAXREC, (float)(LSEQ - 1));
    for (int it = lane; it < NH * NTAP; it += 64) {
        int h = it & 7, s = it >> 3;
        float f  = fph[h];
        float ph = fph[8 + h];
        float p = (tf + ph) + (float)(s - 16) * f;
        p = fminf(fmaxf(p, lo), hi);
        float p0 = floorf(p);
        float w  = p - p0;
        int i0 = (int)p0;
        if (i0 >= LSEQ - 1) { i0 = LSEQ - 2; w = 1.0f; }   // off1 = off0+1 always valid
        _Float16 hw = (_Float16)w;
        unsigned u = ((unsigned)i0 << 16) |
                     (unsigned)__builtin_bit_cast(unsigned short, hw);
        tab[(size_t)pos * (NH * NTAP) + it] = u;
    }
}

// ---------------------------------------------------------------------------
// Kernel 2: bf16 MFMA GEMM, BM=BN=64, BK=64, 4 waves (2x2), double-buffered.
// COMPACT: write silu'd result only for taps (n&63)<33 into kern33[pos][h][33].
// else:    write full f32 silu'd [M,512].
// ---------------------------------------------------------------------------
template<bool COMPACT>
__global__ __launch_bounds__(256) void gemm_mfma64(
    const __bf16* __restrict__ At, const __bf16* __restrict__ Bt,
    const float* __restrict__ bias, float* __restrict__ C)
{
    __shared__ __bf16 As[2][64 * 64];
    __shared__ __bf16 Bs[2][64 * 64];

    int bm = blockIdx.x, bn = blockIdx.y;
    int tid  = threadIdx.x;
    int lane = tid & 63;
    int wid  = tid >> 6;
    int wr = wid >> 1, wc = wid & 1;
    int lg = lane >> 4, l15 = lane & 15;

    const __bf16* Abase = At + (size_t)bm * 8 * 4096;
    const __bf16* Bbase = Bt + (size_t)bn * 8 * 4096;

    int offA[2][2], offB[2][2];
    #pragma unroll
    for (int mi = 0; mi < 2; ++mi) {
        int row = wr * 32 + mi * 16 + l15;
        #pragma unroll
        for (int ks = 0; ks < 2; ++ks)
            offA[mi][ks] = row * 128 + (((ks << 6) | (lg << 4)) ^ ((row & 7) << 4));
    }
    #pragma unroll
    for (int ni = 0; ni < 2; ++ni) {
        int n = wc * 32 + ni * 16 + l15;
        #pragma unroll
        for (int ks = 0; ks < 2; ++ks)
            offB[ni][ks] = n * 128 + (((ks << 6) | (lg << 4)) ^ ((n & 7) << 4));
    }

    f32x4 acc[2][2] = {};

    auto stage = [&](int b, int kt) {
        const __bf16* ga = Abase + (size_t)kt * 4096 + tid * 8;
        const __bf16* gb = Bbase + (size_t)kt * 4096 + tid * 8;
        __bf16* la = &As[b][tid * 8];
        __bf16* lb = &Bs[b][tid * 8];
        #pragma unroll
        for (int c = 0; c < 2; ++c) gload_lds16(ga + c * 2048, la + c * 2048);
        #pragma unroll
        for (int c = 0; c < 2; ++c) gload_lds16(gb + c * 2048, lb + c * 2048);
    };

    stage(0, 0);
    #pragma unroll
    for (int kt = 0; kt < 8; ++kt) {
        int cur = kt & 1;
        if (kt < 7) stage(cur ^ 1, kt + 1);
        __builtin_amdgcn_sched_barrier(0);
        if (kt < 7) asm volatile("s_waitcnt vmcnt(4)" ::: "memory");
        else        asm volatile("s_waitcnt vmcnt(0)" ::: "memory");
        __builtin_amdgcn_s_barrier();
        const char* ab = (const char*)&As[cur][0];
        const char* bb = (const char*)&Bs[cur][0];
        #pragma unroll
        for (int ks = 0; ks < 2; ++ks) {
            bf16x8 af[2], bfr[2];
            #pragma unroll
            for (int mi = 0; mi < 2; ++mi) af[mi]  = *(const bf16x8*)(ab + offA[mi][ks]);
            #pragma unroll
            for (int ni = 0; ni < 2; ++ni) bfr[ni] = *(const bf16x8*)(bb + offB[ni][ks]);
            #pragma unroll
            for (int mi = 0; mi < 2; ++mi)
                #pragma unroll
                for (int ni = 0; ni < 2; ++ni)
                    acc[mi][ni] = __builtin_amdgcn_mfma_f32_16x16x32_bf16(
                        af[mi], bfr[ni], acc[mi][ni], 0, 0, 0);
        }
        __builtin_amdgcn_s_barrier();
    }

    // C/D frag: col = l&15, row = (l>>4)*4 + j
    int n0 = bn * 64 + wc * 32 + l15;
    #pragma unroll
    for (int ni = 0; ni < 2; ++ni) {
        int n = n0 + ni * 16;
        float bv = bias ? bias[n] : 0.0f;
        #pragma unroll
        for (int mi = 0; mi < 2; ++mi) {
            int m = bm * 64 + wr * 32 + mi * 16 + lg * 4;
            #pragma unroll
            for (int j = 0; j < 4; ++j) {
                float v = silu_f(acc[mi][ni][j] + bv);
                if (COMPACT) {
                    int h = n >> 6, sc = n & 63;
                    if (sc < NTAP)
                        C[((size_t)(m + j) * NH + h) * NTAP + sc] = v;
                } else {
                    C[(size_t)(m + j) * 512 + n] = v;
                }
            }
        }
    }
}

// ---------------------------------------------------------------------------
// Kernel 3: gather conv. One wave per (t,h); lane = dim d; batch = blockIdx.y.
// XCD-aware block swizzle: contiguous t-chunks per XCD -> L2-resident window.
// Writes hidden as bf16 in the tiled GEMM layout.
// ---------------------------------------------------------------------------
__global__ __launch_bounds__(256, 4) void gather_conv(
    const float* __restrict__ x, const unsigned* __restrict__ tab,
    const float* __restrict__ kern33, __bf16* __restrict__ hb)
{
    int wid  = threadIdx.x >> 6;
    int lane = threadIdx.x & 63;
    int bid  = blockIdx.x;                       // 4096 = 8 XCDs * 512
    int nb   = ((bid & 7) << 9) | (bid >> 3);    // bijective XCD-chunked swizzle
    int wix  = nb * 4 + wid;                     // t*8 + h
    int h = wix & 7, t = wix >> 3;
    int b = blockIdx.y;

    const char* xbase = (const char*)x + (size_t)b * (LSEQ * CHN * 4);
    int dlane = (h * HD + lane) * 4;
    int pos = b * LSEQ + t;
    const unsigned* tp = tab + (size_t)pos * (NH * NTAP) + h;
    const float*    kp = kern33 + ((size_t)pos * NH + h) * NTAP;

    float acc0 = 0.0f, acc1 = 0.0f;
    #pragma unroll
    for (int s = 0; s < NTAP; ++s) {
        unsigned u = tp[s * 8];
        float k = kp[s];
        float w = (float)__builtin_bit_cast(_Float16, (unsigned short)(u & 0xFFFFu));
        int off0 = (int)(u >> 16) << 11;
        float g0 = *(const float*)(xbase + (off0 + dlane));
        float g1 = *(const float*)(xbase + (off0 + 2048 + dlane));
        float t1 = k * w;
        acc0 = fmaf(k - t1, g0, acc0);
        acc1 = fmaf(t1, g1, acc1);
    }
    float acc = acc0 + acc1;

    // tiled+permuted+swizzled bf16 write; k-index = h*64 + lane, kt = h
    int tile = (pos >> 6) * 8 + h;
    int rowL = pos & 63;
    int d = lane, blk = d >> 5, kk = d & 31;
    int colp = blk * 32 + (kk & 3) + (((kk >> 4) & 1) << 2) + (((kk & 15) >> 2) << 3);
    int byteS = (colp * 2) ^ ((rowL & 7) << 4);
    hb[(size_t)tile * 4096 + rowL * 64 + (byteS >> 1)] = (__bf16)acc;
}

// ---------------------------------------------------------------------------
extern "C" void kernel_launch(void* const* d_in, const int* in_sizes, int n_in,
                              void* d_out, int out_size, void* d_ws, size_t ws_size,
                              hipStream_t stream)
{
    const float* x        = (const float*)d_in[0];
    const float* wave_w   = (const float*)d_in[1];
    const float* wave_b   = (const float*)d_in[2];
    const float* kernel_w = (const float*)d_in[3];
    const float* kernel_b = (const float*)d_in[4];
    const float* out_w    = (const float*)d_in[5];
    float* out = (float*)d_out;

    char* ws = (char*)d_ws;
    unsigned* tab    = (unsigned*)ws;  ws += (size_t)NPOS * NH * NTAP * 4;  // 4.33 MB
    float*    kern33 = (float*)ws;     ws += (size_t)NPOS * NH * NTAP * 4;  // 4.33 MB
    __bf16*   xb     = (__bf16*)ws;    ws += (size_t)NPOS * CHN * 2;        // 4 MB
    __bf16*   kwb    = (__bf16*)ws;    ws += (size_t)CHN * CHN * 2;         // 0.5 MB
    __bf16*   owb    = (__bf16*)ws;    ws += (size_t)CHN * CHN * 2;         // 0.5 MB
    __bf16*   hidb   = xb;  // xb dead after GEMM1

    convert_w<<<dim3(CHN * CHN / 8 / 256, 2), 256, 0, stream>>>(kernel_w, kwb, out_w, owb);

    wave_taps<<<NPOS, 64, 0, stream>>>(x, wave_w, wave_b, tab, xb);

    dim3 gg(NPOS / 64, CHN / 64);
    gemm_mfma64<true><<<gg, 256, 0, stream>>>(xb, kwb, kernel_b, kern33);

    gather_conv<<<dim3(LSEQ * NH / 4, 2), 256, 0, stream>>>(x, tab, kern33, hidb);

    gemm_mfma64<false><<<gg, 256, 0, stream>>>(hidb, owb, nullptr, out);
}